// Round 1
// baseline (43.293 us; speedup 1.0000x reference)
//
#include <hip/hip_runtime.h>

// NGramsEmbedding: out[t, :] = sum_{n=0..2} W[idx[n, t], :]
//   idx: [3, 512*128] int32 (n-stride = T), W: [50257, 256] f32, out: [T, 256] f32
// One wave (64 lanes) per token: each lane handles 4 consecutive floats (float4),
// so each gather / store is exactly one fully-coalesced 1 KB wave transaction.

__global__ __launch_bounds__(256) void ngrams_embed_kernel(
    const int* __restrict__ idx,
    const float* __restrict__ weight,
    float* __restrict__ out,
    int T)  // number of tokens = seq*batch
{
    const int gtid = blockIdx.x * blockDim.x + threadIdx.x;
    const int wave = gtid >> 6;          // one wave per token
    const int lane = threadIdx.x & 63;
    if (wave >= T) return;

    // three n-gram indices for this token
    const long long r0 = idx[wave];
    const long long r1 = idx[wave + T];
    const long long r2 = idx[wave + 2 * T];

    const float4* __restrict__ w0 = reinterpret_cast<const float4*>(weight + r0 * 256);
    const float4* __restrict__ w1 = reinterpret_cast<const float4*>(weight + r1 * 256);
    const float4* __restrict__ w2 = reinterpret_cast<const float4*>(weight + r2 * 256);

    const float4 a = w0[lane];
    const float4 b = w1[lane];
    const float4 c = w2[lane];

    float4 s;
    s.x = a.x + b.x + c.x;
    s.y = a.y + b.y + c.y;
    s.z = a.z + b.z + c.z;
    s.w = a.w + b.w + c.w;

    reinterpret_cast<float4*>(out + (long long)wave * 256)[lane] = s;
}

extern "C" void kernel_launch(void* const* d_in, const int* in_sizes, int n_in,
                              void* d_out, int out_size, void* d_ws, size_t ws_size,
                              hipStream_t stream) {
    const int*   idx    = (const int*)d_in[0];    // [3, seq, batch] flattened
    const float* weight = (const float*)d_in[1];  // [V, 256]
    float*       out    = (float*)d_out;          // [seq, batch, 256]

    const int T = in_sizes[0] / 3;                // tokens = seq*batch = 65536

    const int block = 256;                         // 4 waves -> 4 tokens per block
    const int grid  = (T * 64 + block - 1) / block;
    ngrams_embed_kernel<<<grid, block, 0, stream>>>(idx, weight, out, T);
}

// Round 3
// 42.158 us; speedup vs baseline: 1.0269x; 1.0269x over previous
//
#include <hip/hip_runtime.h>

// NGramsEmbedding: out[t, :] = sum_{n=0..2} W[idx[n, t], :]
//   idx: [3, T] int32 (n-stride = T), W: [50257, 256] f32, out: [T, 256] f32
//
// R3: 4 tokens per wave (fixed nontemporal builtin typing).
//  - idx loads: one int4 per n-gram (4 consecutive tokens) -> 3 loads total.
//  - 12 independent 16B gathers in flight per wave (4x MLP vs R1).
//  - readfirstlane the row indices -> scalar base + lane offset addressing.
//  - nontemporal stores: 64 MB output stream doesn't thrash the 4 MiB/XCD L2,
//    keeping L2 capacity for the randomly-gathered weight rows.

typedef float f32x4 __attribute__((ext_vector_type(4)));
typedef int   i32x4 __attribute__((ext_vector_type(4)));

__global__ __launch_bounds__(256) void ngrams_embed_kernel(
    const int* __restrict__ idx,
    const float* __restrict__ weight,
    float* __restrict__ out,
    int T)  // tokens = seq*batch (multiple of 4)
{
    const int gtid = blockIdx.x * blockDim.x + threadIdx.x;
    const int wave = gtid >> 6;
    const int lane = threadIdx.x & 63;
    const int t0 = wave * 4;
    if (t0 >= T) return;

    // 12 indices via three 16B loads (wave-uniform)
    const i32x4 i0 = *reinterpret_cast<const i32x4*>(idx + t0);
    const i32x4 i1 = *reinterpret_cast<const i32x4*>(idx + t0 + T);
    const i32x4 i2 = *reinterpret_cast<const i32x4*>(idx + t0 + 2 * T);

    const int rows[3][4] = {
        {i0.x, i0.y, i0.z, i0.w},
        {i1.x, i1.y, i1.z, i1.w},
        {i2.x, i2.y, i2.z, i2.w},
    };

    const f32x4* __restrict__ wv = reinterpret_cast<const f32x4*>(weight);

    // Issue all 12 gathers; compiler schedules loads back-to-back, waits once.
    f32x4 v[3][4];
#pragma unroll
    for (int n = 0; n < 3; ++n) {
#pragma unroll
        for (int j = 0; j < 4; ++j) {
            // scalar row base (row index is wave-uniform)
            const long long r = (long long)__builtin_amdgcn_readfirstlane(rows[n][j]);
            v[n][j] = wv[r * 64 + lane];   // 64 f32x4 per 256-float row
        }
    }

#pragma unroll
    for (int j = 0; j < 4; ++j) {
        const f32x4 s = v[0][j] + v[1][j] + v[2][j];
        f32x4* dst = reinterpret_cast<f32x4*>(out + (long long)(t0 + j) * 256) + lane;
        __builtin_nontemporal_store(s, dst);
    }
}

extern "C" void kernel_launch(void* const* d_in, const int* in_sizes, int n_in,
                              void* d_out, int out_size, void* d_ws, size_t ws_size,
                              hipStream_t stream) {
    const int*   idx    = (const int*)d_in[0];    // [3, seq, batch] flattened
    const float* weight = (const float*)d_in[1];  // [V, 256]
    float*       out    = (float*)d_out;          // [seq, batch, 256]

    const int T = in_sizes[0] / 3;                // tokens = 65536

    const int waves = (T + 3) / 4;                // 4 tokens per wave
    const int block = 256;                        // 4 waves per block
    const int grid  = (waves * 64 + block - 1) / block;
    ngrams_embed_kernel<<<grid, block, 0, stream>>>(idx, weight, out, T);
}

// Round 4
// 31.640 us; speedup vs baseline: 1.3683x; 1.3324x over previous
//
#include <hip/hip_runtime.h>

// NGramsEmbedding: out[t, :] = sum_{n=0..2} W[idx[n, t], :]
//   idx: [3, T] int32, W: [50257, 256] f32, out: [T, 256] f32
//
// R4: XCD-partitioned column slices.
//   Weight columns split into 8 slices of 32 floats (128 B). Block b handles
//   slice (b & 7); round-robin dispatch puts equal slices on the same XCD, so
//   each XCD's L2 only sees a 6.4 MB slice of W (vs the full 51.5 MB),
//   letting the ~3.7x row reuse hit in L2 instead of going to fabric/HBM.
//   Each wave: 8 tokens per instruction (8 lanes x 16 B = one 128 B slice),
//   32 tokens per wave, 12 gathers + 4 NT stores in flight.

typedef float f32x4 __attribute__((ext_vector_type(4)));

__global__ __launch_bounds__(256) void ngrams_embed_slice_kernel(
    const int* __restrict__ idx,
    const float* __restrict__ weight,
    float* __restrict__ out,
    int T)
{
    const int slice = blockIdx.x & 7;          // XCD id under round-robin dispatch
    const int tblk  = blockIdx.x >> 3;         // token block (128 tokens)
    const int wave  = threadIdx.x >> 6;        // 0..3
    const int lane  = threadIdx.x & 63;
    const int sub   = lane >> 3;               // token-within-group 0..7
    const int cpart = lane & 7;                // 16B chunk within 128B slice

    const int tw = tblk * 128 + wave * 32;     // 32 tokens per wave

    // 12 indices per lane (8-fold redundant across lanes -> L1 broadcast)
    int rows[4][3];
#pragma unroll
    for (int g = 0; g < 4; ++g) {
        const int tk = tw + g * 8 + sub;
#pragma unroll
        for (int n = 0; n < 3; ++n)
            rows[g][n] = idx[n * T + tk];
    }

    // 12 independent 16B gathers (8 scattered 128B segments per wave instr)
    const float* wbase = weight + slice * 32 + cpart * 4;
    f32x4 v[4][3];
#pragma unroll
    for (int g = 0; g < 4; ++g)
#pragma unroll
        for (int n = 0; n < 3; ++n)
            v[g][n] = *reinterpret_cast<const f32x4*>(wbase + (long long)rows[g][n] * 256);

#pragma unroll
    for (int g = 0; g < 4; ++g) {
        const int tk = tw + g * 8 + sub;
        const f32x4 s = v[g][0] + v[g][1] + v[g][2];
        f32x4* dst = reinterpret_cast<f32x4*>(out + (long long)tk * 256 + slice * 32 + cpart * 4);
        __builtin_nontemporal_store(s, dst);
    }
}

extern "C" void kernel_launch(void* const* d_in, const int* in_sizes, int n_in,
                              void* d_out, int out_size, void* d_ws, size_t ws_size,
                              hipStream_t stream) {
    const int*   idx    = (const int*)d_in[0];    // [3, seq, batch] flattened
    const float* weight = (const float*)d_in[1];  // [V, 256]
    float*       out    = (float*)d_out;          // [seq, batch, 256]

    const int T = in_sizes[0] / 3;                // tokens = 65536 (mult of 128)

    const int block = 256;
    const int grid  = (T / 128) * 8;              // 8 slices x token blocks
    ngrams_embed_slice_kernel<<<grid, block, 0, stream>>>(idx, weight, out, T);
}